// Round 1
// baseline (1869.448 us; speedup 1.0000x reference)
//
#include <hip/hip_runtime.h>
#include <math.h>

// Problem constants
#define HH 240
#define WW 320
#define HWSZ (240*320)      // 76800
#define NN 2

// Workspace layout (bytes, 256-aligned)
#define OFF_W1T   0                  // w1t[ci][co*9+k]  : 128*576 f32 = 294912 B
#define OFF_W3T   294912             // w3t[ci][co*9+k]  : 64*576  f32 = 147456 B
#define OFF_W2T   442368             // w2t[c][j]        : 64*54   f32 = 13824 B
#define OFF_COEFT 456192             // coeft[c][oc*6+m] : 64*384  f32 = 98304 B
#define OFF_BN    554496             // [sbr(64), bbr2(64), s3(64), b3(64)] = 1024 B
#define OFF_U     557056             // u buffer: 2*64*76800 f32 = 39321600 B
// total ws need: 39,878,656 B (~40 MB)

// ---------------- prep: weight transposes + BN folds ----------------
__global__ void prep_k(const float* __restrict__ w1, const float* __restrict__ w3,
                       const float* __restrict__ w2, const float* __restrict__ coef,
                       const float* __restrict__ coef_bias,
                       const float* __restrict__ brg, const float* __restrict__ brb,
                       const float* __restrict__ brm, const float* __restrict__ brv,
                       const float* __restrict__ g3, const float* __restrict__ b3,
                       const float* __restrict__ m3, const float* __restrict__ v3,
                       float* __restrict__ ws) {
    int id = blockIdx.x * 256 + threadIdx.x;
    // w1t[ci*576 + co*9 + k] = w1[co*1152 + ci*9 + k]   (w1: [64][128][3][3])
    if (id < 73728) {
        int ci = id / 576; int r = id - ci * 576; int co = r / 9; int k = r - co * 9;
        ws[OFF_W1T/4 + id] = w1[co*1152 + ci*9 + k];
        return;
    }
    id -= 73728;
    // w3t[ci*576 + co*9 + k] = w3[co*576 + ci*9 + k]    (w3: [64][64][3][3])
    if (id < 36864) {
        int ci = id / 576; int r = id - ci * 576; int co = r / 9; int k = r - co * 9;
        ws[OFF_W3T/4 + id] = w3[co*576 + ci*9 + k];
        return;
    }
    id -= 36864;
    // w2t[c*54 + j] = w2[j*64 + c]                      (w2: [54][64][1][1])
    if (id < 3456) {
        int c = id / 54; int j = id - c * 54;
        ws[OFF_W2T/4 + id] = w2[j*64 + c];
        return;
    }
    id -= 3456;
    // coeft[c*384 + oc*6 + m] = coef[oc*384 + c*6 + m]  (coef: [64][384][1][1])
    if (id < 24576) {
        int c = id / 384; int r = id - c * 384; int oc = r / 6; int m = r - oc * 6;
        ws[OFF_COEFT/4 + id] = coef[oc*384 + c*6 + m];
        return;
    }
    id -= 24576;
    if (id < 64) {  // br BN fold (+ coef_bias folded in)
        float s = brg[id] * rsqrtf(brv[id] + 1e-5f);
        ws[OFF_BN/4 + id]      = s;
        ws[OFF_BN/4 + 64 + id] = coef_bias[id]*s + brb[id] - brm[id]*s;
        return;
    }
    id -= 64;
    if (id < 64) {  // bn3 fold
        float s = g3[id] * rsqrtf(v3[id] + 1e-5f);
        ws[OFF_BN/4 + 128 + id] = s;
        ws[OFF_BN/4 + 192 + id] = b3[id] - m3[id]*s;
    }
}

// ---------------- kernel 1: conv3x3(cat(feat,weight),128->64)+b1+ReLU -> t ----------------
// block = (32,8) = one pixel/thread, all 64 co accumulated in regs.
// Weights pre-transposed so per-ci weights are contiguous & wave-uniform -> s_load.
__launch_bounds__(256)
__global__ void conv1_k(const float* __restrict__ feat, const float* __restrict__ wgt,
                        const float* __restrict__ w1t, const float* __restrict__ b1,
                        float* __restrict__ tout) {
    __shared__ float tile[340];  // (8+2) x (32+2)
    const int tx = threadIdx.x, ty = threadIdx.y;
    const int x0 = blockIdx.x * 32, y0 = blockIdx.y * 8;
    const int n = blockIdx.z;
    const int x = x0 + tx, y = y0 + ty;
    const int tid = ty * 32 + tx;

    float acc[64];
    #pragma unroll
    for (int i = 0; i < 64; ++i) acc[i] = 0.f;

    for (int ci = 0; ci < 128; ++ci) {
        const float* plane = (ci < 64) ? (feat + (n*64 + ci) * HWSZ)
                                       : (wgt  + (n*64 + ci - 64) * HWSZ);
        for (int i = tid; i < 340; i += 256) {
            int ly = i / 34, lx = i - ly * 34;
            int gy = y0 - 1 + ly, gx = x0 - 1 + lx;
            float v = 0.f;
            if (gy >= 0 && gy < HH && gx >= 0 && gx < WW) v = plane[gy * WW + gx];
            tile[i] = v;
        }
        __syncthreads();
        float p[9];
        #pragma unroll
        for (int ky = 0; ky < 3; ++ky)
            #pragma unroll
            for (int kx = 0; kx < 3; ++kx)
                p[ky*3 + kx] = tile[(ty + ky) * 34 + tx + kx];
        __syncthreads();  // patches in regs; tile may be overwritten next iter
        const float* wci = w1t + ci * 576;
        #pragma unroll
        for (int co = 0; co < 64; ++co) {
            #pragma unroll
            for (int k = 0; k < 9; ++k)
                acc[co] = fmaf(wci[co*9 + k], p[k], acc[co]);
        }
    }
    #pragma unroll
    for (int co = 0; co < 64; ++co) {
        float v = acc[co] + b1[co];
        tout[(n*64 + co) * HWSZ + y * WW + x] = fmaxf(v, 0.f);
    }
}

// ---------------- kernel 2: bases(1x1) + einsum + coef(1x1) + BN + ReLU -> u ----------------
// out[oc] = sum_c sum_m coef[oc,c,m] * ( sum_l bases[m,l] * patch[c,l] )
__launch_bounds__(256)
__global__ void fuse2_k(const float* __restrict__ feat, const float* __restrict__ tin,
                        const float* __restrict__ w2t, const float* __restrict__ b2,
                        const float* __restrict__ coeft, const float* __restrict__ bn,
                        float* __restrict__ uout) {
    __shared__ float smem[16 * 340];  // 16 channels x (10x34) tile
    const int tx = threadIdx.x, ty = threadIdx.y;
    const int x0 = blockIdx.x * 32, y0 = blockIdx.y * 8;
    const int n = blockIdx.z;
    const int x = x0 + tx, y = y0 + ty;
    const int tid = ty * 32 + tx;

    // Phase A: bases[j] = b2[j] + sum_c w2[j,c] * t[c] at this pixel
    float bases[54];
    #pragma unroll
    for (int j = 0; j < 54; ++j) bases[j] = b2[j];
    for (int c = 0; c < 64; ++c) {
        float tv = tin[(n*64 + c) * HWSZ + y * WW + x];
        const float* w2c = w2t + c * 54;
        #pragma unroll
        for (int j = 0; j < 54; ++j) bases[j] = fmaf(w2c[j], tv, bases[j]);
    }

    // Phase B: accumulate coef contraction over c in chunks of 16 (LDS-staged patches)
    float out[64];
    #pragma unroll
    for (int i = 0; i < 64; ++i) out[i] = 0.f;

    for (int cc = 0; cc < 64; cc += 16) {
        __syncthreads();  // protect previous chunk's reads
        for (int i = tid; i < 16 * 340; i += 256) {
            int cl = i / 340; int r = i - cl * 340;
            int ly = r / 34, lx = r - ly * 34;
            int gy = y0 - 1 + ly, gx = x0 - 1 + lx;
            float v = 0.f;
            if (gy >= 0 && gy < HH && gx >= 0 && gx < WW)
                v = feat[(n*64 + cc + cl) * HWSZ + gy * WW + gx];
            smem[i] = v;
        }
        __syncthreads();
        for (int cl = 0; cl < 16; ++cl) {
            float p[9];
            #pragma unroll
            for (int ky = 0; ky < 3; ++ky)
                #pragma unroll
                for (int kx = 0; kx < 3; ++kx)
                    p[ky*3 + kx] = smem[cl*340 + (ty + ky)*34 + tx + kx];
            float s[6];
            #pragma unroll
            for (int m = 0; m < 6; ++m) {
                float a = 0.f;
                #pragma unroll
                for (int l = 0; l < 9; ++l) a = fmaf(bases[m*9 + l], p[l], a);
                s[m] = a;
            }
            const float* cf = coeft + (cc + cl) * 384;
            #pragma unroll
            for (int oc = 0; oc < 64; ++oc) {
                #pragma unroll
                for (int m = 0; m < 6; ++m)
                    out[oc] = fmaf(cf[oc*6 + m], s[m], out[oc]);
            }
        }
    }

    #pragma unroll
    for (int oc = 0; oc < 64; ++oc) {
        float v = fmaxf(fmaf(out[oc], bn[oc], bn[64 + oc]), 0.f);  // BN(+coef_bias)+ReLU
        uout[(n*64 + oc) * HWSZ + y * WW + x] = v;
    }
}

// ---------------- kernel 3: conv3x3(u,64->64) + BN + ReLU -> d_out ----------------
__launch_bounds__(256)
__global__ void conv3_k(const float* __restrict__ uin, const float* __restrict__ w3t,
                        const float* __restrict__ bn, float* __restrict__ outp) {
    __shared__ float tile[340];
    const int tx = threadIdx.x, ty = threadIdx.y;
    const int x0 = blockIdx.x * 32, y0 = blockIdx.y * 8;
    const int n = blockIdx.z;
    const int x = x0 + tx, y = y0 + ty;
    const int tid = ty * 32 + tx;

    float acc[64];
    #pragma unroll
    for (int i = 0; i < 64; ++i) acc[i] = 0.f;

    for (int ci = 0; ci < 64; ++ci) {
        const float* plane = uin + (n*64 + ci) * HWSZ;
        for (int i = tid; i < 340; i += 256) {
            int ly = i / 34, lx = i - ly * 34;
            int gy = y0 - 1 + ly, gx = x0 - 1 + lx;
            float v = 0.f;
            if (gy >= 0 && gy < HH && gx >= 0 && gx < WW) v = plane[gy * WW + gx];
            tile[i] = v;
        }
        __syncthreads();
        float p[9];
        #pragma unroll
        for (int ky = 0; ky < 3; ++ky)
            #pragma unroll
            for (int kx = 0; kx < 3; ++kx)
                p[ky*3 + kx] = tile[(ty + ky) * 34 + tx + kx];
        __syncthreads();
        const float* wci = w3t + ci * 576;
        #pragma unroll
        for (int co = 0; co < 64; ++co) {
            #pragma unroll
            for (int k = 0; k < 9; ++k)
                acc[co] = fmaf(wci[co*9 + k], p[k], acc[co]);
        }
    }
    #pragma unroll
    for (int co = 0; co < 64; ++co) {
        float v = fmaxf(fmaf(acc[co], bn[128 + co], bn[192 + co]), 0.f);
        outp[(n*64 + co) * HWSZ + y * WW + x] = v;
    }
}

extern "C" void kernel_launch(void* const* d_in, const int* in_sizes, int n_in,
                              void* d_out, int out_size, void* d_ws, size_t ws_size,
                              hipStream_t stream) {
    const float* feat      = (const float*)d_in[0];
    const float* wgt       = (const float*)d_in[1];
    const float* w1        = (const float*)d_in[2];
    const float* b1        = (const float*)d_in[3];
    const float* w2        = (const float*)d_in[4];
    const float* b2        = (const float*)d_in[5];
    const float* coef      = (const float*)d_in[6];
    const float* coef_bias = (const float*)d_in[7];
    const float* brg       = (const float*)d_in[8];
    const float* brb       = (const float*)d_in[9];
    const float* brm       = (const float*)d_in[10];
    const float* brv       = (const float*)d_in[11];
    const float* w3        = (const float*)d_in[12];
    const float* g3        = (const float*)d_in[13];
    const float* b3        = (const float*)d_in[14];
    const float* m3        = (const float*)d_in[15];
    const float* v3        = (const float*)d_in[16];

    float* out = (float*)d_out;
    float* ws  = (float*)d_ws;

    // prep: 138752 work items = 542 blocks of 256 exactly
    prep_k<<<542, 256, 0, stream>>>(w1, w3, w2, coef, coef_bias,
                                    brg, brb, brm, brv, g3, b3, m3, v3, ws);

    dim3 grid(WW/32, HH/8, NN);   // (10, 30, 2)
    dim3 blk(32, 8);

    // t lives in d_out between k1 and k2 (exactly out_size floats)
    conv1_k<<<grid, blk, 0, stream>>>(feat, wgt, ws + OFF_W1T/4, b1, out);
    fuse2_k<<<grid, blk, 0, stream>>>(feat, out, ws + OFF_W2T/4, b2,
                                      ws + OFF_COEFT/4, ws + OFF_BN/4, ws + OFF_U/4);
    conv3_k<<<grid, blk, 0, stream>>>(ws + OFF_U/4, ws + OFF_W3T/4, ws + OFF_BN/4, out);
}